// Round 3
// baseline (2400.728 us; speedup 1.0000x reference)
//
#include <hip/hip_runtime.h>
#include <math.h>

// Problem constants
#define NB 2
#define NC 256
#define CG 16
#define HH 192
#define WW 192
#define HO 190
#define PP 144

// LDS: 7152 floats = 28608 B -> 5 blocks/CU (vs 4 before).
// Band layout: row r at r*196, pads [0..3] (always zero), data [4..195].
//   Reads use addr r*196 + 2 + v + dj  (v+dj-2 in data coords): left spill
//   hits own-row pads [2,3], right spill hits next row's pads [0,1].
// Epilogue aliases: edge rows 0..11 (same layout) + red[192][25] at 2352.
#define SMEM_FLOATS 7152

// ---------------------------------------------------------------------------
// Kernel 1: correlation-decomposed Gram (identical math/order to round 2 ->
// bit-identical results). Changes: float4 staging, 20-step bands (less LDS),
// group-of-5 register prefetch of xa/xb, conflict-free stride-25 reduce.
// ---------------------------------------------------------------------------
__global__ __launch_bounds__(192, 4) void gram_kernel(const float* __restrict__ x,
                                                      double* __restrict__ gram)
{
    __shared__ float smem[SMEM_FLOATS];
    float* const red_s = smem + 2352;

    const int v = threadIdx.x;                // column 0..191
    int r = blockIdx.x;
    const int bg = r / 72; r -= bg * 72;
    int c2 = 0;
    while (r >= (c2 + 2) / 2) { r -= (c2 + 2) / 2; ++c2; }
    const int c1a = 2 * r;
    int c1b = 2 * r + 1;
    const bool bval = (c1b <= c2);
    if (!bval) c1b = c2;
    const int b = bg >> 4, g = bg & 15;

    const float* __restrict__ xa  = x + ((size_t)(b * NC + g * CG + c1a)) * (HH * WW);
    const float* __restrict__ xb  = x + ((size_t)(b * NC + g * CG + c1b)) * (HH * WW);
    const float* __restrict__ x2g = x + ((size_t)(b * NC + g * CG + c2 )) * (HH * WW);

    // zero the pad slots of rows 0..24 once; stores below never touch pads
    if (v < 100) smem[(v >> 2) * 196 + (v & 3)] = 0.f;

    float mid[2][25];
#pragma unroll
    for (int o = 0; o < 25; ++o) { mid[0][o] = 0.f; mid[1][o] = 0.f; }

    float win[5][5];
    float ca[5], cb[5], na[5], nb[5];
#pragma unroll
    for (int k = 0; k < 5; ++k) {             // prefetch steps 0..4 (u=2..6)
        ca[k] = xa[(size_t)(2 + k) * WW + v];
        cb[k] = xb[(size_t)(2 + k) * WW + v];
    }

// one u-step: local step LS within band (u = u0+LS), phase K = LS%5.
// staged row r holds abs row u0-2+r and lives in slot r%5; new row LS+4.
#define USTEP(K, LS)                                                          \
    {                                                                         \
        const int lrow = (LS) + 4;                                            \
        _Pragma("unroll")                                                     \
        for (int dj = 0; dj < 5; ++dj)                                        \
            win[((K) + 4) % 5][dj] = smem[lrow * 196 + 2 + v + dj];           \
        const float a1 = ca[(K)];                                             \
        const float b1 = cb[(K)];                                             \
        _Pragma("unroll")                                                     \
        for (int kk = 0; kk < 5; ++kk) {                                      \
            _Pragma("unroll")                                                 \
            for (int dj = 0; dj < 5; ++dj) {                                  \
                const float xv = win[((K) + kk) % 5][dj];                     \
                mid[0][kk * 5 + dj] = fmaf(a1, xv, mid[0][kk * 5 + dj]);      \
                mid[1][kk * 5 + dj] = fmaf(b1, xv, mid[1][kk * 5 + dj]);      \
            }                                                                 \
        }                                                                     \
    }

    for (int band = 0; band < 10; ++band) {
        const int u0 = 2 + band * 20;
        const int steps = (band < 9) ? 20 : 8;
        const int nrows = steps + 4;          // 24 or 12
        const int row0 = u0 - 2;
        __syncthreads();
        // float4 staging: nrows * 48 float4 across 192 threads
        for (int it = 0; it < nrows / 4; ++it) {
            const int idx = it * 192 + v;
            const int rr = idx / 48;
            const int c4 = (idx - rr * 48) * 4;
            const float4 val = *(const float4*)(x2g + (size_t)(row0 + rr) * WW + c4);
            *(float4*)(&smem[rr * 196 + 4 + c4]) = val;
        }
        __syncthreads();
        // prologue: staged rows 0..3 -> slots 0..3
#pragma unroll
        for (int k = 0; k < 4; ++k)
#pragma unroll
        for (int dj = 0; dj < 5; ++dj)
            win[k][dj] = smem[k * 196 + 2 + v + dj];

        if (band < 9) {
#pragma unroll
            for (int grp = 0; grp < 4; ++grp) {
                const int unext = 2 + band * 20 + grp * 5 + 5;  // next group's u
#pragma unroll
                for (int k = 0; k < 5; ++k) {
                    na[k] = xa[(size_t)(unext + k) * WW + v];
                    nb[k] = xb[(size_t)(unext + k) * WW + v];
                }
                USTEP(0, grp * 5 + 0) USTEP(1, grp * 5 + 1) USTEP(2, grp * 5 + 2)
                USTEP(3, grp * 5 + 3) USTEP(4, grp * 5 + 4)
#pragma unroll
                for (int k = 0; k < 5; ++k) { ca[k] = na[k]; cb[k] = nb[k]; }
            }
        } else {
            // band 9: 8 steps. group 0 (locals 0..4), prefetch locals 5..7
#pragma unroll
            for (int k = 0; k < 5; ++k) {
                na[k] = xa[(size_t)(187 + k) * WW + v];   // u=187..191 (189+ unused)
                nb[k] = xb[(size_t)(187 + k) * WW + v];
            }
            USTEP(0, 0) USTEP(1, 1) USTEP(2, 2) USTEP(3, 3) USTEP(4, 4)
#pragma unroll
            for (int k = 0; k < 5; ++k) { ca[k] = na[k]; cb[k] = nb[k]; }
            USTEP(0, 5) USTEP(1, 6) USTEP(2, 7)
        }
    }
#undef USTEP

    // stage edge buffer: buf i<6 -> abs row i-2 (OOB zero), i>=6 -> 188+(i-6)
    __syncthreads();
    for (int i = 0; i < 12; ++i) {
        const int ar = (i < 6) ? (i - 2) : (188 + i - 6);
        const float val = (ar >= 0 && ar <= 191) ? x2g[(size_t)ar * WW + v] : 0.f;
        smem[i * 196 + 4 + v] = val;
    }
    __syncthreads();

    double* const gp = gram + (size_t)bg * (PP * PP);

#pragma unroll
    for (int i1 = 0; i1 < 3; ++i1) {
        const int ra = (i1 == 0) ? 0 : ((i1 == 1) ? 1 : 190);
        const int rb = (i1 == 0) ? 1 : ((i1 == 1) ? 190 : 191);
#pragma unroll
        for (int c = 0; c < 2; ++c) {
            const float* __restrict__ xc = (c == 0) ? xa : xb;
            const float xra = xc[(size_t)ra * WW + v];
            const float xrb = xc[(size_t)rb * WW + v];
#pragma unroll
            for (int k = 0; k < 5; ++k) {
                const int bufa = (ra < 2) ? (ra + k) : (ra + k - 184);
                const int bufb = (rb < 2) ? (rb + k) : (rb + k - 184);
#pragma unroll
                for (int dj = 0; dj < 5; ++dj) {
                    float cw = mid[c][k * 5 + dj];
                    cw = fmaf(xra, smem[bufa * 196 + 2 + v + dj], cw);
                    cw = fmaf(xrb, smem[bufb * 196 + 2 + v + dj], cw);
                    red_s[v * 25 + k * 5 + dj] = cw;
                }
            }
            __syncthreads();
            float e0 = 0.f, e1 = 0.f, e190 = 0.f, e191 = 0.f;
            if (v < 25) {
                e0   = red_s[0 * 25 + v];
                e1   = red_s[1 * 25 + v];
                e190 = red_s[190 * 25 + v];
                e191 = red_s[191 * 25 + v];
            }
            __syncthreads();
            // tree reduce over columns: 192 -> 96 -> ... -> 3 (stride 25: no conflicts)
#pragma unroll
            for (int s = 96; s >= 3; s >>= 1) {
                for (int idx = v; idx < s * 25; idx += 192) {
                    const int vv = idx / 25, o = idx - vv * 25;
                    red_s[vv * 25 + o] += red_s[(vv + s) * 25 + o];
                }
                __syncthreads();
            }
            if (v < 25 && (c == 0 || bval)) {
                const int di = v / 5 - 2, dj = v - (v / 5) * 5 - 2;
                const int i2 = i1 + di;
                if (i2 >= 0 && i2 <= 2) {
                    const float S = red_s[0 * 25 + v] + red_s[1 * 25 + v] + red_s[2 * 25 + v];
                    const int c1 = (c == 0) ? c1a : c1b;
#pragma unroll
                    for (int j1 = 0; j1 < 3; ++j1) {
                        const int j2 = j1 + dj;
                        if (j2 < 0 || j2 > 2) continue;
                        const float W = S - ((j1 == 0) ? (e190 + e191)
                                          : (j1 == 1) ? (e0 + e191)
                                                      : (e0 + e1));
                        const int p = c1 * 9 + i1 * 3 + j1;
                        const int q = c2 * 9 + i2 * 3 + j2;
                        gp[p * PP + q] = (double)W;
                        if (c1 != c2) gp[q * PP + p] = (double)W;
                    }
                }
            }
            __syncthreads();   // red reused by next (i1,c)
        }
    }
}

// ---------------------------------------------------------------------------
// Kernel 2: per-group argmin (f64 d2, first-min tiebreak), bincount over both
// batches, stable top-3 (smallest index on count ties, matching lax.top_k).
// ---------------------------------------------------------------------------
__global__ __launch_bounds__(320) void topk_kernel(const double* __restrict__ gram,
                                                   float* __restrict__ pf,
                                                   int* __restrict__ pi)
{
    const int g = blockIdx.x;
    __shared__ double sdiag[2][PP];
    __shared__ int counts[PP];
    const int tid = threadIdx.x;
    if (tid < PP) counts[tid] = 0;
    if (tid < 2 * PP) {
        const int b = tid / PP, p = tid % PP;
        const double* gb = gram + (size_t)(b * 16 + g) * (PP * PP);
        sdiag[b][p] = gb[p * PP + p];
    }
    __syncthreads();
    if (tid < 2 * PP) {
        const int b = tid / PP, p = tid % PP;
        const double* row = gram + ((size_t)(b * 16 + g) * PP + p) * PP;
        const double sp = sdiag[b][p];
        double best = 1e300;
        int bi = 0;
        for (int q = 0; q < PP; ++q) {
            if (q == p) continue;
            const double d2 = sp + sdiag[b][q] - 2.0 * row[q];
            if (d2 < best) { best = d2; bi = q; }   // strict < : first occurrence
        }
        atomicAdd(&counts[bi], 1);
    }
    __syncthreads();
    if (tid == 0) {
        int sel[3], cv[3];
        for (int o = 0; o < 3; ++o) {
            int bc = -1, bp = 0;
            for (int p = 0; p < PP; ++p) {
                bool taken = false;
                for (int u = 0; u < o; ++u) if (sel[u] == p) taken = true;
                if (!taken && counts[p] > bc) { bc = counts[p]; bp = p; } // > keeps lowest idx
            }
            sel[o] = bp; cv[o] = bc;
        }
        const int tot = cv[0] + cv[1] + cv[2];
        for (int o = 0; o < 3; ++o) {
            pf[g * 4 + o] = (float)cv[o];
            pi[g * 4 + o] = sel[o];
        }
        pf[g * 4 + 3] = (float)tot;
    }
}

// ---------------------------------------------------------------------------
// Kernel 3: fused scale->floor->fold stencil. Division replaced by bit-exact
// f64 reciprocal-multiply (see analysis: total<=288 => exact quotients are
// >=2^-34 rel from any f32 midpoint, f64 error <=2^-51; ties impossible).
// Each rounding step reproduces the reference's f32 RN sequence exactly.
// Template splits interior pixels (no clamps/masks) from edges.
// ---------------------------------------------------------------------------
template <bool EDGE>
__device__ __forceinline__ void motif_quad(const float* __restrict__ x,
                                           const float* __restrict__ pf,
                                           const int* __restrict__ pi,
                                           float* __restrict__ out,
                                           int b, int ch, int h, int w0)
{
    const int g = ch >> 4;
    const size_t base = ((size_t)(b * NC + ch)) * (HH * WW);
    const float4 xv4 = *(const float4*)(x + base + (size_t)h * WW + w0);
    const float xs[4] = {xv4.x, xv4.y, xv4.z, xv4.w};
    const double xd[4] = {(double)xs[0], (double)xs[1], (double)xs[2], (double)xs[3]};
    float acc[4] = {0.f, 0.f, 0.f, 0.f};
    const float total = pf[g * 4 + 3];
    const double invd = 1.0 / (double)total;

#pragma unroll
    for (int o = 0; o < 3; ++o) {
        const int p = pi[g * 4 + o];
        const double cfd = (double)pf[g * 4 + o];
        const int co = p / 9;
        const int kk = p - co * 9;
        const int io = kk / 3, jo = kk - (kk / 3) * 3;
        const float* Rb = x + ((size_t)(b * NC + g * CG + co)) * (HH * WW);
#pragma unroll
        for (int i = 0; i < 3; ++i) {
            const int ho = h - i;
            bool rowok = true;
            int hr = ho + io;
            if (EDGE) {
                rowok = (ho >= 0) && (ho < HO);
                hr = hr < 0 ? 0 : (hr > HH - 1 ? HH - 1 : hr);
            }
            const float* row = Rb + (size_t)hr * WW;
            float rv[6];
#pragma unroll
            for (int u = 0; u < 6; ++u) {
                int col = w0 - 2 + jo + u;
                if (EDGE) col = col < 0 ? 0 : (col > WW - 1 ? WW - 1 : col);
                rv[u] = row[col];
            }
#pragma unroll
            for (int j = 0; j < 3; ++j)
#pragma unroll
            for (int q = 0; q < 4; ++q) {
                const float r2 = rv[q - j + 2];
                const double d1 = xd[q] * (double)r2;   // exact (48-bit)
                const float t1 = (float)d1;             // == __fmul_rn(x, r)
                const double d2 = (double)t1 * cfd;     // exact (33-bit)
                const float t2 = (float)d2;             // == __fmul_rn(t1, cf)
                const float qf = (float)((double)t2 * invd); // == __fdiv_rn(t2,total)
                const float vfl = floorf(qf);
                if (EDGE) {
                    const int wo = w0 + q - j;
                    const bool ok = rowok && (wo >= 0) && (wo < HO);
                    acc[q] += ok ? vfl : 0.f;
                } else {
                    acc[q] += vfl;
                }
            }
        }
    }
    float4 ov = make_float4(acc[0], acc[1], acc[2], acc[3]);
    *(float4*)(out + base + (size_t)h * WW + w0) = ov;
}

__global__ __launch_bounds__(256) void out_kernel(const float* __restrict__ x,
                                                  const float* __restrict__ pf,
                                                  const int* __restrict__ pi,
                                                  float* __restrict__ out)
{
    const int gid = blockIdx.x * 256 + threadIdx.x;
    const int w4 = gid % 48;
    int t = gid / 48;
    const int h = t % HH; t /= HH;
    const int ch = t % NC;
    const int b = t / NC;
    const int w0 = w4 * 4;

    if (h >= 2 && h <= 189 && w4 >= 1 && w4 <= 46)
        motif_quad<false>(x, pf, pi, out, b, ch, h, w0);
    else
        motif_quad<true>(x, pf, pi, out, b, ch, h, w0);
}

// ---------------------------------------------------------------------------
extern "C" void kernel_launch(void* const* d_in, const int* in_sizes, int n_in,
                              void* d_out, int out_size, void* d_ws, size_t ws_size,
                              hipStream_t stream)
{
    const float* x = (const float*)d_in[0];
    float* out = (float*)d_out;

    double* gram = (double*)d_ws;
    const size_t gram_bytes = (size_t)32 * PP * PP * sizeof(double); // 5,308,416 B
    float* pf = (float*)((char*)d_ws + gram_bytes);
    int* pi = (int*)((char*)d_ws + gram_bytes + 256);

    gram_kernel<<<32 * 72, 192, 0, stream>>>(x, gram);
    topk_kernel<<<16, 320, 0, stream>>>(gram, pf, pi);
    out_kernel<<<18432, 256, 0, stream>>>(x, pf, pi, out);
}

// Round 4
// 1394.685 us; speedup vs baseline: 1.7213x; 1.7213x over previous
//
#include <hip/hip_runtime.h>
#include <math.h>

// Problem constants
#define NB 2
#define NC 256
#define CG 16
#define HH 192
#define WW 192
#define HO 190
#define PP 144

// LDS: 7152 floats = 28608 B -> 4 blocks/CU at waves_per_eu(3).
// Band layout: row r at r*196, pads [0..3] (always zero), data [4..195].
//   Reads use addr r*196 + 2 + v + dj: left spill hits own-row pads [2,3],
//   right spill hits next row's pads [0,1].
// Epilogue aliases: edge rows 0..11 (same layout) + red[192][25] at 2352.
#define SMEM_FLOATS 7152

// ---------------------------------------------------------------------------
// Kernel 1: correlation-decomposed Gram (same FMA order as rounds 1-3 ->
// bit-identical results). float4 staging, 20-step bands, in-place rotating
// 5-deep register prefetch of xa/xb, conflict-free stride-25 reduce.
// __launch_bounds__(192,3): 3 waves/EU is FEASIBLE with 28.6KB LDS (4 blocks
// = 12 waves/CU); VGPR cap ~170 >> ~100 live -> no scratch spill (round-3's
// (192,4) was infeasible -> VGPR 64 -> 8GB scratch traffic).
// ---------------------------------------------------------------------------
__global__ __launch_bounds__(192, 3) void gram_kernel(const float* __restrict__ x,
                                                      double* __restrict__ gram)
{
    __shared__ float smem[SMEM_FLOATS];
    float* const red_s = smem + 2352;

    const int v = threadIdx.x;                // column 0..191
    int r = blockIdx.x;
    const int bg = r / 72; r -= bg * 72;
    int c2 = 0;
    while (r >= (c2 + 2) / 2) { r -= (c2 + 2) / 2; ++c2; }
    const int c1a = 2 * r;
    int c1b = 2 * r + 1;
    const bool bval = (c1b <= c2);
    if (!bval) c1b = c2;
    const int b = bg >> 4, g = bg & 15;

    const float* __restrict__ xa  = x + ((size_t)(b * NC + g * CG + c1a)) * (HH * WW);
    const float* __restrict__ xb  = x + ((size_t)(b * NC + g * CG + c1b)) * (HH * WW);
    const float* __restrict__ x2g = x + ((size_t)(b * NC + g * CG + c2 )) * (HH * WW);

    // zero the pad slots of rows 0..24 once; stores below never touch pads
    if (v < 100) smem[(v >> 2) * 196 + (v & 3)] = 0.f;

    float mid[2][25];
#pragma unroll
    for (int o = 0; o < 25; ++o) { mid[0][o] = 0.f; mid[1][o] = 0.f; }

    float win[5][5];
    float ca[5], cb[5];
#pragma unroll
    for (int k = 0; k < 5; ++k) {             // prefetch steps 0..4 (u=2..6)
        ca[k] = xa[(size_t)(2 + k) * WW + v];
        cb[k] = xb[(size_t)(2 + k) * WW + v];
    }

// one u-step: local step LS within band (u = u0+LS), phase K = LS%5.
// Consumes ca[K]/cb[K]; if PF, refills the slot from row u0+LS+5 (5 ahead).
#define USTEP(K, LS, PF)                                                      \
    {                                                                         \
        const int lrow = (LS) + 4;                                            \
        _Pragma("unroll")                                                     \
        for (int dj = 0; dj < 5; ++dj)                                        \
            win[((K) + 4) % 5][dj] = smem[lrow * 196 + 2 + v + dj];           \
        const float a1 = ca[(K)];                                             \
        const float b1 = cb[(K)];                                             \
        if (PF) {                                                             \
            ca[(K)] = xa[(size_t)(u0 + (LS) + 5) * WW + v];                   \
            cb[(K)] = xb[(size_t)(u0 + (LS) + 5) * WW + v];                   \
        }                                                                     \
        _Pragma("unroll")                                                     \
        for (int kk = 0; kk < 5; ++kk) {                                      \
            _Pragma("unroll")                                                 \
            for (int dj = 0; dj < 5; ++dj) {                                  \
                const float xv = win[((K) + kk) % 5][dj];                     \
                mid[0][kk * 5 + dj] = fmaf(a1, xv, mid[0][kk * 5 + dj]);      \
                mid[1][kk * 5 + dj] = fmaf(b1, xv, mid[1][kk * 5 + dj]);      \
            }                                                                 \
        }                                                                     \
    }

    for (int band = 0; band < 10; ++band) {
        const int u0 = 2 + band * 20;
        const int steps = (band < 9) ? 20 : 8;
        const int nrows = steps + 4;          // 24 or 12
        const int row0 = u0 - 2;
        __syncthreads();
        // float4 staging: nrows * 48 float4 across 192 threads
        for (int it = 0; it < nrows / 4; ++it) {
            const int idx = it * 192 + v;
            const int rr = idx / 48;
            const int c4 = (idx - rr * 48) * 4;
            const float4 val = *(const float4*)(x2g + (size_t)(row0 + rr) * WW + c4);
            *(float4*)(&smem[rr * 196 + 4 + c4]) = val;
        }
        __syncthreads();
        // prologue: staged rows 0..3 -> slots 0..3
#pragma unroll
        for (int k = 0; k < 4; ++k)
#pragma unroll
        for (int dj = 0; dj < 5; ++dj)
            win[k][dj] = smem[k * 196 + 2 + v + dj];

        if (band < 9) {
#pragma unroll
            for (int grp = 0; grp < 4; ++grp) {
                USTEP(0, grp * 5 + 0, true) USTEP(1, grp * 5 + 1, true)
                USTEP(2, grp * 5 + 2, true) USTEP(3, grp * 5 + 3, true)
                USTEP(4, grp * 5 + 4, true)
            }
        } else {
            // band 9: 8 steps; steps 0..4 refill u=187..191 (last rotation),
            // steps 5..7 consume ca[0..2] = u 187..189, no further prefetch.
            USTEP(0, 0, true) USTEP(1, 1, true) USTEP(2, 2, true)
            USTEP(3, 3, true) USTEP(4, 4, true)
            USTEP(0, 5, false) USTEP(1, 6, false) USTEP(2, 7, false)
        }
    }
#undef USTEP

    // stage edge buffer: buf i<6 -> abs row i-2 (OOB zero), i>=6 -> 188+(i-6)
    __syncthreads();
    for (int i = 0; i < 12; ++i) {
        const int ar = (i < 6) ? (i - 2) : (188 + i - 6);
        const float val = (ar >= 0 && ar <= 191) ? x2g[(size_t)ar * WW + v] : 0.f;
        smem[i * 196 + 4 + v] = val;
    }
    __syncthreads();

    double* const gp = gram + (size_t)bg * (PP * PP);

#pragma unroll
    for (int i1 = 0; i1 < 3; ++i1) {
        const int ra = (i1 == 0) ? 0 : ((i1 == 1) ? 1 : 190);
        const int rb = (i1 == 0) ? 1 : ((i1 == 1) ? 190 : 191);
#pragma unroll
        for (int c = 0; c < 2; ++c) {
            const float* __restrict__ xc = (c == 0) ? xa : xb;
            const float xra = xc[(size_t)ra * WW + v];
            const float xrb = xc[(size_t)rb * WW + v];
#pragma unroll
            for (int k = 0; k < 5; ++k) {
                const int bufa = (ra < 2) ? (ra + k) : (ra + k - 184);
                const int bufb = (rb < 2) ? (rb + k) : (rb + k - 184);
#pragma unroll
                for (int dj = 0; dj < 5; ++dj) {
                    float cw = mid[c][k * 5 + dj];
                    cw = fmaf(xra, smem[bufa * 196 + 2 + v + dj], cw);
                    cw = fmaf(xrb, smem[bufb * 196 + 2 + v + dj], cw);
                    red_s[v * 25 + k * 5 + dj] = cw;
                }
            }
            __syncthreads();
            float e0 = 0.f, e1 = 0.f, e190 = 0.f, e191 = 0.f;
            if (v < 25) {
                e0   = red_s[0 * 25 + v];
                e1   = red_s[1 * 25 + v];
                e190 = red_s[190 * 25 + v];
                e191 = red_s[191 * 25 + v];
            }
            __syncthreads();
            // tree reduce over columns: 192 -> 96 -> ... -> 3 (stride 25: conflict-free)
#pragma unroll
            for (int s = 96; s >= 3; s >>= 1) {
                for (int idx = v; idx < s * 25; idx += 192) {
                    const int vv = idx / 25, o = idx - vv * 25;
                    red_s[vv * 25 + o] += red_s[(vv + s) * 25 + o];
                }
                __syncthreads();
            }
            if (v < 25 && (c == 0 || bval)) {
                const int di = v / 5 - 2, dj = v - (v / 5) * 5 - 2;
                const int i2 = i1 + di;
                if (i2 >= 0 && i2 <= 2) {
                    const float S = red_s[0 * 25 + v] + red_s[1 * 25 + v] + red_s[2 * 25 + v];
                    const int c1 = (c == 0) ? c1a : c1b;
#pragma unroll
                    for (int j1 = 0; j1 < 3; ++j1) {
                        const int j2 = j1 + dj;
                        if (j2 < 0 || j2 > 2) continue;
                        const float W = S - ((j1 == 0) ? (e190 + e191)
                                          : (j1 == 1) ? (e0 + e191)
                                                      : (e0 + e1));
                        const int p = c1 * 9 + i1 * 3 + j1;
                        const int q = c2 * 9 + i2 * 3 + j2;
                        gp[p * PP + q] = (double)W;
                        if (c1 != c2) gp[q * PP + p] = (double)W;
                    }
                }
            }
            __syncthreads();   // red reused by next (i1,c)
        }
    }
}

// ---------------------------------------------------------------------------
// Kernel 2: per-group argmin (f64 d2, first-min tiebreak), bincount over both
// batches, stable top-3 (smallest index on count ties, matching lax.top_k).
// ---------------------------------------------------------------------------
__global__ __launch_bounds__(320) void topk_kernel(const double* __restrict__ gram,
                                                   float* __restrict__ pf,
                                                   int* __restrict__ pi)
{
    const int g = blockIdx.x;
    __shared__ double sdiag[2][PP];
    __shared__ int counts[PP];
    const int tid = threadIdx.x;
    if (tid < PP) counts[tid] = 0;
    if (tid < 2 * PP) {
        const int b = tid / PP, p = tid % PP;
        const double* gb = gram + (size_t)(b * 16 + g) * (PP * PP);
        sdiag[b][p] = gb[p * PP + p];
    }
    __syncthreads();
    if (tid < 2 * PP) {
        const int b = tid / PP, p = tid % PP;
        const double* row = gram + ((size_t)(b * 16 + g) * PP + p) * PP;
        const double sp = sdiag[b][p];
        double best = 1e300;
        int bi = 0;
        for (int q = 0; q < PP; ++q) {
            if (q == p) continue;
            const double d2 = sp + sdiag[b][q] - 2.0 * row[q];
            if (d2 < best) { best = d2; bi = q; }   // strict < : first occurrence
        }
        atomicAdd(&counts[bi], 1);
    }
    __syncthreads();
    if (tid == 0) {
        int sel[3], cv[3];
        for (int o = 0; o < 3; ++o) {
            int bc = -1, bp = 0;
            for (int p = 0; p < PP; ++p) {
                bool taken = false;
                for (int u = 0; u < o; ++u) if (sel[u] == p) taken = true;
                if (!taken && counts[p] > bc) { bc = counts[p]; bp = p; } // > keeps lowest idx
            }
            sel[o] = bp; cv[o] = bc;
        }
        const int tot = cv[0] + cv[1] + cv[2];
        for (int o = 0; o < 3; ++o) {
            pf[g * 4 + o] = (float)cv[o];
            pi[g * 4 + o] = sel[o];
        }
        pf[g * 4 + 3] = (float)tot;
    }
}

// ---------------------------------------------------------------------------
// Kernel 3: fused scale->floor->fold stencil. t1,t2 are plain f32 muls
// (== __fmul_rn == reference ops). Division via f64 reciprocal-multiply:
// bit-exact (total<=288 => exact quotients >=2^-34 rel from any f32 rounding
// midpoint, exact ties impossible, f64 error <=2^-52 -> identical rounding).
// Floors are small ints; the <=27-term f32 accumulation is exact, so
// summation order is irrelevant. Interior/edge split via template.
// ---------------------------------------------------------------------------
template <bool EDGE>
__device__ __forceinline__ void motif_quad(const float* __restrict__ x,
                                           const float* __restrict__ pf,
                                           const int* __restrict__ pi,
                                           float* __restrict__ out,
                                           int b, int ch, int h, int w0)
{
    const int g = ch >> 4;
    const size_t base = ((size_t)(b * NC + ch)) * (HH * WW);
    const float4 xv4 = *(const float4*)(x + base + (size_t)h * WW + w0);
    const float xs[4] = {xv4.x, xv4.y, xv4.z, xv4.w};
    float acc[4] = {0.f, 0.f, 0.f, 0.f};
    const float total = pf[g * 4 + 3];
    const double invd = 1.0 / (double)total;

#pragma unroll
    for (int o = 0; o < 3; ++o) {
        const int p = pi[g * 4 + o];
        const float cff = pf[g * 4 + o];
        const int co = p / 9;
        const int kk = p - co * 9;
        const int io = kk / 3, jo = kk - (kk / 3) * 3;
        const float* Rb = x + ((size_t)(b * NC + g * CG + co)) * (HH * WW);
#pragma unroll
        for (int i = 0; i < 3; ++i) {
            const int ho = h - i;
            bool rowok = true;
            int hr = ho + io;
            if (EDGE) {
                rowok = (ho >= 0) && (ho < HO);
                hr = hr < 0 ? 0 : (hr > HH - 1 ? HH - 1 : hr);
            }
            const float* row = Rb + (size_t)hr * WW;
            float rv[6];
#pragma unroll
            for (int u = 0; u < 6; ++u) {
                int col = w0 - 2 + jo + u;
                if (EDGE) col = col < 0 ? 0 : (col > WW - 1 ? WW - 1 : col);
                rv[u] = row[col];
            }
#pragma unroll
            for (int j = 0; j < 3; ++j)
#pragma unroll
            for (int q = 0; q < 4; ++q) {
                const float r2 = rv[q - j + 2];
                const float t1 = xs[q] * r2;                  // == __fmul_rn
                const float t2 = t1 * cff;                    // == __fmul_rn
                const float qf = (float)((double)t2 * invd);  // == __fdiv_rn(t2,total)
                const float vfl = floorf(qf);
                if (EDGE) {
                    const int wo = w0 + q - j;
                    const bool ok = rowok && (wo >= 0) && (wo < HO);
                    acc[q] += ok ? vfl : 0.f;
                } else {
                    acc[q] += vfl;
                }
            }
        }
    }
    float4 ov = make_float4(acc[0], acc[1], acc[2], acc[3]);
    *(float4*)(out + base + (size_t)h * WW + w0) = ov;
}

__global__ __launch_bounds__(256) void out_kernel(const float* __restrict__ x,
                                                  const float* __restrict__ pf,
                                                  const int* __restrict__ pi,
                                                  float* __restrict__ out)
{
    const int gid = blockIdx.x * 256 + threadIdx.x;
    const int w4 = gid % 48;
    int t = gid / 48;
    const int h = t % HH; t /= HH;
    const int ch = t % NC;
    const int b = t / NC;
    const int w0 = w4 * 4;

    if (h >= 2 && h <= 189 && w4 >= 1 && w4 <= 46)
        motif_quad<false>(x, pf, pi, out, b, ch, h, w0);
    else
        motif_quad<true>(x, pf, pi, out, b, ch, h, w0);
}

// ---------------------------------------------------------------------------
extern "C" void kernel_launch(void* const* d_in, const int* in_sizes, int n_in,
                              void* d_out, int out_size, void* d_ws, size_t ws_size,
                              hipStream_t stream)
{
    const float* x = (const float*)d_in[0];
    float* out = (float*)d_out;

    double* gram = (double*)d_ws;
    const size_t gram_bytes = (size_t)32 * PP * PP * sizeof(double); // 5,308,416 B
    float* pf = (float*)((char*)d_ws + gram_bytes);
    int* pi = (int*)((char*)d_ws + gram_bytes + 256);

    gram_kernel<<<32 * 72, 192, 0, stream>>>(x, gram);
    topk_kernel<<<16, 320, 0, stream>>>(gram, pf, pi);
    out_kernel<<<18432, 256, 0, stream>>>(x, pf, pi, out);
}

// Round 5
// 541.954 us; speedup vs baseline: 4.4298x; 2.5734x over previous
//
#include <hip/hip_runtime.h>
#include <math.h>

// Problem constants
#define NB 2
#define NC 256
#define CG 16
#define HH 192
#define WW 192
#define HO 190
#define PP 144

// LDS: 7348 floats = 29392 B -> 5 blocks/CU.
// Band area: up to 36 rows x 196 (rows: [0..3]=pads always zero, [4..195]=data).
//   Window reads at r*196 + 2+v+dj: left spill -> own pads [2,3], right spill
//   -> next row's pads [0,1] (never written by staging -> stay zero).
// Epilogue: edge rows 0..11 (same layout), row 12 = permanent zero guard
//   (slots [0,1] serve edge-row-11 right spill), red[192][25] at 2548.
#define SMEM_FLOATS 7348

// ---------------------------------------------------------------------------
// Kernel 1: correlation-decomposed Gram. Same FMA order as rounds 1-4 ->
// bit-identical gram. NO min-waves hint (empirical: compiler caps VGPR at
// 256/minwaves -> 84/64 -> massive scratch spill in rounds 3-4).
// 32-step bands (12 barriers), 8-deep xa/xb prefetch ring, XCD-clustered
// block swizzle (blocks of one channel-group cluster on one XCD -> L2 hits).
// ---------------------------------------------------------------------------
__global__ __launch_bounds__(192) void gram_kernel(const float* __restrict__ x,
                                                   double* __restrict__ gram)
{
    __shared__ float smem[SMEM_FLOATS];
    float* const red_s = smem + 2548;

    const int v = threadIdx.x;                // column 0..191
    // XCD-clustered decode: bid%8 = intended XCD; half-group hg = bg*2+half
    // (36 blocks) pinned to XCD hg%8. Bijective over 2304 blocks.
    {
    }
    const int bid = blockIdx.x;
    const int vx = bid & 7;
    const int tq = bid >> 3;                  // 0..287
    const int idxw = tq / 36;                 // 0..7
    const int rr0 = tq - idxw * 36;           // 0..35
    const int hg = idxw * 8 + vx;             // 0..63
    const int bg = hg >> 1;
    int r = rr0 + 36 * (hg & 1);              // 0..71
    int c2 = 0;
    while (r >= (c2 + 2) / 2) { r -= (c2 + 2) / 2; ++c2; }
    const int c1a = 2 * r;
    int c1b = 2 * r + 1;
    const bool bval = (c1b <= c2);
    if (!bval) c1b = c2;
    const int b = bg >> 4, g = bg & 15;

    const float* __restrict__ xa  = x + ((size_t)(b * NC + g * CG + c1a)) * (HH * WW);
    const float* __restrict__ xb  = x + ((size_t)(b * NC + g * CG + c1b)) * (HH * WW);
    const float* __restrict__ x2g = x + ((size_t)(b * NC + g * CG + c2 )) * (HH * WW);

    // zero pad slots [0..3] of rows 0..36 once (148 slots); staging never
    // writes pads, so they stay zero for the whole kernel.
    if (v < 148) smem[(v >> 2) * 196 + (v & 3)] = 0.f;

    float mid[2][25];
#pragma unroll
    for (int o = 0; o < 25; ++o) { mid[0][o] = 0.f; mid[1][o] = 0.f; }

    float win[5][5];
    float ca[8], cb[8];
#pragma unroll
    for (int k = 0; k < 8; ++k) {             // prefetch rows 2..9 (steps 0..7)
        ca[k] = xa[(size_t)(2 + k) * WW + v];
        cb[k] = xb[(size_t)(2 + k) * WW + v];
    }

// one u-step: local step LS within band (u = u0+LS). Window ring slot of
// staged row R is R%5; prefetch ring slot of row u is (u-2)%8 = LS%8.
#define USTEP(LS, PF)                                                         \
    {                                                                         \
        constexpr int W5 = (LS) % 5;                                          \
        constexpr int P8 = (LS) % 8;                                          \
        const int lrow = (LS) + 4;                                            \
        _Pragma("unroll")                                                     \
        for (int dj = 0; dj < 5; ++dj)                                        \
            win[(W5 + 4) % 5][dj] = smem[lrow * 196 + 2 + v + dj];            \
        const float a1 = ca[P8];                                              \
        const float b1 = cb[P8];                                              \
        if (PF) {                                                             \
            ca[P8] = xa[(size_t)(u0 + (LS) + 8) * WW + v];                    \
            cb[P8] = xb[(size_t)(u0 + (LS) + 8) * WW + v];                    \
        }                                                                     \
        _Pragma("unroll")                                                     \
        for (int kk = 0; kk < 5; ++kk) {                                      \
            _Pragma("unroll")                                                 \
            for (int dj = 0; dj < 5; ++dj) {                                  \
                const float xv = win[(W5 + kk) % 5][dj];                      \
                mid[0][kk * 5 + dj] = fmaf(a1, xv, mid[0][kk * 5 + dj]);      \
                mid[1][kk * 5 + dj] = fmaf(b1, xv, mid[1][kk * 5 + dj]);      \
            }                                                                 \
        }                                                                     \
    }

#define PROLOGUE                                                              \
    _Pragma("unroll")                                                         \
    for (int k = 0; k < 4; ++k)                                               \
        _Pragma("unroll")                                                     \
        for (int dj = 0; dj < 5; ++dj)                                        \
            win[k][dj] = smem[k * 196 + 2 + v + dj];

    // bands 0..4: 32 steps each (u = 2..161), staging 36 rows
    for (int band = 0; band < 5; ++band) {
        const int u0 = 2 + band * 32;
        __syncthreads();
        for (int it = 0; it < 9; ++it) {      // 36 rows * 48 float4 / 192 thr
            const int idx = it * 192 + v;
            const int rr2 = idx / 48;
            const int c4 = (idx - rr2 * 48) * 4;
            const float4 val = *(const float4*)(x2g + (size_t)(u0 - 2 + rr2) * WW + c4);
            *(float4*)(&smem[rr2 * 196 + 4 + c4]) = val;
        }
        __syncthreads();
        PROLOGUE
        USTEP(0,1)  USTEP(1,1)  USTEP(2,1)  USTEP(3,1)
        USTEP(4,1)  USTEP(5,1)  USTEP(6,1)  USTEP(7,1)
        USTEP(8,1)  USTEP(9,1)  USTEP(10,1) USTEP(11,1)
        USTEP(12,1) USTEP(13,1) USTEP(14,1) USTEP(15,1)
        USTEP(16,1) USTEP(17,1) USTEP(18,1) USTEP(19,1)
        USTEP(20,1) USTEP(21,1) USTEP(22,1) USTEP(23,1)
        USTEP(24,1) USTEP(25,1) USTEP(26,1) USTEP(27,1)
        USTEP(28,1) USTEP(29,1) USTEP(30,1) USTEP(31,1)
    }
    // band 5: 28 steps (u = 162..189), staging rows 160..191 (32 rows).
    // Prefetch while u0+LS+8 <= 191 -> LS <= 21.
    {
        const int u0 = 162;
        __syncthreads();
        for (int it = 0; it < 8; ++it) {
            const int idx = it * 192 + v;
            const int rr2 = idx / 48;
            const int c4 = (idx - rr2 * 48) * 4;
            const float4 val = *(const float4*)(x2g + (size_t)(160 + rr2) * WW + c4);
            *(float4*)(&smem[rr2 * 196 + 4 + c4]) = val;
        }
        __syncthreads();
        PROLOGUE
        USTEP(0,1)  USTEP(1,1)  USTEP(2,1)  USTEP(3,1)
        USTEP(4,1)  USTEP(5,1)  USTEP(6,1)  USTEP(7,1)
        USTEP(8,1)  USTEP(9,1)  USTEP(10,1) USTEP(11,1)
        USTEP(12,1) USTEP(13,1) USTEP(14,1) USTEP(15,1)
        USTEP(16,1) USTEP(17,1) USTEP(18,1) USTEP(19,1)
        USTEP(20,1) USTEP(21,1)
        USTEP(22,0) USTEP(23,0) USTEP(24,0) USTEP(25,0)
        USTEP(26,0) USTEP(27,0)
    }
#undef USTEP
#undef PROLOGUE

    // stage edge buffer: buf i<6 -> abs row i-2 (OOB zero), i>=6 -> 188+(i-6).
    // Row 12 (floats 2352..2547) is the zero guard: its pads [0,1] catch edge
    // row 11's right spill; red_s starts at 2548 so reduce writes never
    // corrupt them (fixes rounds 1-4 latent aliasing).
    __syncthreads();
    for (int i = 0; i < 12; ++i) {
        const int ar = (i < 6) ? (i - 2) : (188 + i - 6);
        const float val = (ar >= 0 && ar <= 191) ? x2g[(size_t)ar * WW + v] : 0.f;
        smem[i * 196 + 4 + v] = val;
    }
    __syncthreads();

    double* const gp = gram + (size_t)bg * (PP * PP);

#pragma unroll
    for (int i1 = 0; i1 < 3; ++i1) {
        const int ra = (i1 == 0) ? 0 : ((i1 == 1) ? 1 : 190);
        const int rb = (i1 == 0) ? 1 : ((i1 == 1) ? 190 : 191);
#pragma unroll
        for (int c = 0; c < 2; ++c) {
            const float* __restrict__ xc = (c == 0) ? xa : xb;
            const float xra = xc[(size_t)ra * WW + v];
            const float xrb = xc[(size_t)rb * WW + v];
#pragma unroll
            for (int k = 0; k < 5; ++k) {
                const int bufa = (ra < 2) ? (ra + k) : (ra + k - 184);
                const int bufb = (rb < 2) ? (rb + k) : (rb + k - 184);
#pragma unroll
                for (int dj = 0; dj < 5; ++dj) {
                    float cw = mid[c][k * 5 + dj];
                    cw = fmaf(xra, smem[bufa * 196 + 2 + v + dj], cw);
                    cw = fmaf(xrb, smem[bufb * 196 + 2 + v + dj], cw);
                    red_s[v * 25 + k * 5 + dj] = cw;
                }
            }
            __syncthreads();
            float e0 = 0.f, e1 = 0.f, e190 = 0.f, e191 = 0.f;
            if (v < 25) {
                e0   = red_s[0 * 25 + v];
                e1   = red_s[1 * 25 + v];
                e190 = red_s[190 * 25 + v];
                e191 = red_s[191 * 25 + v];
            }
            __syncthreads();
            // tree reduce over columns: 192 -> 96 -> ... -> 3 (stride 25: conflict-free)
#pragma unroll
            for (int s = 96; s >= 3; s >>= 1) {
                for (int idx = v; idx < s * 25; idx += 192) {
                    const int vv = idx / 25, o = idx - vv * 25;
                    red_s[vv * 25 + o] += red_s[(vv + s) * 25 + o];
                }
                __syncthreads();
            }
            if (v < 25 && (c == 0 || bval)) {
                const int di = v / 5 - 2, dj = v - (v / 5) * 5 - 2;
                const int i2 = i1 + di;
                if (i2 >= 0 && i2 <= 2) {
                    const float S = red_s[0 * 25 + v] + red_s[1 * 25 + v] + red_s[2 * 25 + v];
                    const int c1 = (c == 0) ? c1a : c1b;
#pragma unroll
                    for (int j1 = 0; j1 < 3; ++j1) {
                        const int j2 = j1 + dj;
                        if (j2 < 0 || j2 > 2) continue;
                        const float W = S - ((j1 == 0) ? (e190 + e191)
                                          : (j1 == 1) ? (e0 + e191)
                                                      : (e0 + e1));
                        const int p = c1 * 9 + i1 * 3 + j1;
                        const int q = c2 * 9 + i2 * 3 + j2;
                        gp[p * PP + q] = (double)W;
                        if (c1 != c2) gp[q * PP + p] = (double)W;
                    }
                }
            }
            __syncthreads();   // red reused by next (i1,c)
        }
    }
}

// ---------------------------------------------------------------------------
// Kernel 2: per-group argmin (f64 d2, first-min tiebreak), bincount over both
// batches, stable top-3 (smallest index on count ties, matching lax.top_k).
// ---------------------------------------------------------------------------
__global__ __launch_bounds__(320) void topk_kernel(const double* __restrict__ gram,
                                                   float* __restrict__ pf,
                                                   int* __restrict__ pi)
{
    const int g = blockIdx.x;
    __shared__ double sdiag[2][PP];
    __shared__ int counts[PP];
    const int tid = threadIdx.x;
    if (tid < PP) counts[tid] = 0;
    if (tid < 2 * PP) {
        const int b = tid / PP, p = tid % PP;
        const double* gb = gram + (size_t)(b * 16 + g) * (PP * PP);
        sdiag[b][p] = gb[p * PP + p];
    }
    __syncthreads();
    if (tid < 2 * PP) {
        const int b = tid / PP, p = tid % PP;
        const double* row = gram + ((size_t)(b * 16 + g) * PP + p) * PP;
        const double sp = sdiag[b][p];
        double best = 1e300;
        int bi = 0;
        for (int q = 0; q < PP; ++q) {
            if (q == p) continue;
            const double d2 = sp + sdiag[b][q] - 2.0 * row[q];
            if (d2 < best) { best = d2; bi = q; }   // strict < : first occurrence
        }
        atomicAdd(&counts[bi], 1);
    }
    __syncthreads();
    if (tid == 0) {
        int sel[3], cv[3];
        for (int o = 0; o < 3; ++o) {
            int bc = -1, bp = 0;
            for (int p = 0; p < PP; ++p) {
                bool taken = false;
                for (int u = 0; u < o; ++u) if (sel[u] == p) taken = true;
                if (!taken && counts[p] > bc) { bc = counts[p]; bp = p; } // > keeps lowest idx
            }
            sel[o] = bp; cv[o] = bc;
        }
        const int tot = cv[0] + cv[1] + cv[2];
        for (int o = 0; o < 3; ++o) {
            pf[g * 4 + o] = (float)cv[o];
            pi[g * 4 + o] = sel[o];
        }
        pf[g * 4 + 3] = (float)tot;
    }
}

// ---------------------------------------------------------------------------
// Kernel 3: fused scale->floor->fold stencil. t1,t2 are plain f32 muls
// (== __fmul_rn == reference). Division via f64 reciprocal-multiply:
// bit-exact (total<=288 => exact quotients >=2^-34 rel from any f32 rounding
// midpoint, exact ties impossible, f64 error <=2^-52 -> identical rounding).
// Interior and edge handled by SEPARATE KERNELS (round-4's per-thread branch
// put edge lanes in every wave -> both paths executed by all waves).
// ---------------------------------------------------------------------------
template <bool EDGE>
__device__ __forceinline__ void motif_quad(const float* __restrict__ x,
                                           const float* __restrict__ pf,
                                           const int* __restrict__ pi,
                                           float* __restrict__ out,
                                           int b, int ch, int h, int w0)
{
    const int g = ch >> 4;
    const size_t base = ((size_t)(b * NC + ch)) * (HH * WW);
    const float4 xv4 = *(const float4*)(x + base + (size_t)h * WW + w0);
    const float xs[4] = {xv4.x, xv4.y, xv4.z, xv4.w};
    float acc[4] = {0.f, 0.f, 0.f, 0.f};
    const float total = pf[g * 4 + 3];
    const double invd = 1.0 / (double)total;

#pragma unroll
    for (int o = 0; o < 3; ++o) {
        const int p = pi[g * 4 + o];
        const float cff = pf[g * 4 + o];
        const int co = p / 9;
        const int kk = p - co * 9;
        const int io = kk / 3, jo = kk - (kk / 3) * 3;
        const float* Rb = x + ((size_t)(b * NC + g * CG + co)) * (HH * WW);
#pragma unroll
        for (int i = 0; i < 3; ++i) {
            const int ho = h - i;
            bool rowok = true;
            int hr = ho + io;
            if (EDGE) {
                rowok = (ho >= 0) && (ho < HO);
                hr = hr < 0 ? 0 : (hr > HH - 1 ? HH - 1 : hr);
            }
            const float* row = Rb + (size_t)hr * WW;
            float rv[6];
#pragma unroll
            for (int u = 0; u < 6; ++u) {
                int col = w0 - 2 + jo + u;
                if (EDGE) col = col < 0 ? 0 : (col > WW - 1 ? WW - 1 : col);
                rv[u] = row[col];
            }
#pragma unroll
            for (int j = 0; j < 3; ++j)
#pragma unroll
            for (int q = 0; q < 4; ++q) {
                const float r2 = rv[q - j + 2];
                const float t1 = xs[q] * r2;                  // == __fmul_rn
                const float t2 = t1 * cff;                    // == __fmul_rn
                const float qf = (float)((double)t2 * invd);  // == __fdiv_rn(t2,total)
                const float vfl = floorf(qf);
                if (EDGE) {
                    const int wo = w0 + q - j;
                    const bool ok = rowok && (wo >= 0) && (wo < HO);
                    acc[q] += ok ? vfl : 0.f;
                } else {
                    acc[q] += vfl;
                }
            }
        }
    }
    float4 ov = make_float4(acc[0], acc[1], acc[2], acc[3]);
    *(float4*)(out + base + (size_t)h * WW + w0) = ov;
}

// interior: h in [2,189], w4 in [1,46] -> no clamps/masks anywhere.
__global__ __launch_bounds__(256) void out_interior(const float* __restrict__ x,
                                                    const float* __restrict__ pf,
                                                    const int* __restrict__ pi,
                                                    float* __restrict__ out)
{
    const int gid = blockIdx.x * 256 + threadIdx.x;
    const int w4i = gid % 46;
    int t = gid / 46;
    const int h = 2 + t % 188; t /= 188;
    const int ch = t & 255;
    const int b = t >> 8;
    motif_quad<false>(x, pf, pi, out, b, ch, h, (w4i + 1) * 4);
}

// edge: 568 quads per (b,ch): h in {0,1,190,191} x all 48 w4, plus
// h in [2,189] x w4 in {0,47}.
__global__ __launch_bounds__(256) void out_edge(const float* __restrict__ x,
                                                const float* __restrict__ pf,
                                                const int* __restrict__ pi,
                                                float* __restrict__ out)
{
    const int gid = blockIdx.x * 256 + threadIdx.x;
    const int e = gid % 568;
    int t = gid / 568;
    const int ch = t & 255;
    const int b = t >> 8;
    int h, w4;
    if (e < 192) {
        const int hs = e / 48;
        h = (hs < 2) ? hs : 188 + hs;         // 0,1,190,191
        w4 = e % 48;
    } else {
        const int e2 = e - 192;
        h = 2 + (e2 >> 1);
        w4 = (e2 & 1) ? 47 : 0;
    }
    motif_quad<true>(x, pf, pi, out, b, ch, h, w4 * 4);
}

// ---------------------------------------------------------------------------
extern "C" void kernel_launch(void* const* d_in, const int* in_sizes, int n_in,
                              void* d_out, int out_size, void* d_ws, size_t ws_size,
                              hipStream_t stream)
{
    const float* x = (const float*)d_in[0];
    float* out = (float*)d_out;

    double* gram = (double*)d_ws;
    const size_t gram_bytes = (size_t)32 * PP * PP * sizeof(double); // 5,308,416 B
    float* pf = (float*)((char*)d_ws + gram_bytes);
    int* pi = (int*)((char*)d_ws + gram_bytes + 256);

    gram_kernel<<<2304, 192, 0, stream>>>(x, gram);
    topk_kernel<<<16, 320, 0, stream>>>(gram, pf, pi);
    out_interior<<<17296, 256, 0, stream>>>(x, pf, pi, out);  // 2*256*188*46/256
    out_edge<<<1136, 256, 0, stream>>>(x, pf, pi, out);       // 2*256*568/256
}

// Round 6
// 436.749 us; speedup vs baseline: 5.4968x; 1.2409x over previous
//
#include <hip/hip_runtime.h>
#include <math.h>

// Problem constants
#define NB 2
#define NC 256
#define CG 16
#define HH 192
#define WW 192
#define HO 190
#define PP 144

// LDS: 7348 floats = 29392 B -> 5 blocks/CU.
// Band area: up to 34 rows x 196 (row r at r*196: [0..3]=pads always zero,
//   [4..195]=data). Window reads at r*196 + 2+v+dj: left spill -> own pads
//   [2,3], right spill -> next row's pads [0,1] (never written by staging).
// Epilogue: edge rows 0..11 (same layout), row 12 = permanent zero guard
//   (slots [0,1] catch edge-row-11 right spill), red[192][25] at 2548.
#define SMEM_FLOATS 7348

// ---------------------------------------------------------------------------
// Kernel 1: correlation-decomposed Gram. Same FMA order as rounds 1-5 ->
// bit-identical gram. This round: ROLLED 5-phase inner loop (round 2/5's
// ~11K-instr unrolled bodies blew L1I (~32KB) -> 26-30% VALUBusy at any
// occupancy; round-0's rolled loop hit 40%). Body ~2.5KB. 30-step bands
// (6 full + 8-step tail), per-thread-constant staging indices, 5-deep
// xa/xb prefetch ring, XCD-clustered block swizzle (round 5: FETCH 4x down).
// __launch_bounds__(192,2): VGPR cap 128 (~95 live, no spill; 5 blocks/CU).
// ---------------------------------------------------------------------------
__global__ __launch_bounds__(192, 2) void gram_kernel(const float* __restrict__ x,
                                                      double* __restrict__ gram)
{
    __shared__ float smem[SMEM_FLOATS];
    float* const red_s = smem + 2548;

    const int v = threadIdx.x;                // column 0..191
    const int vr = v / 48;                    // staging row sub-index
    const int vc4 = (v - vr * 48) * 4;        // staging col (float4 granules)

    // XCD-clustered decode: bid%8 = intended XCD; half-group hg (36 blocks)
    // pinned to XCD hg%8. Bijective over 2304 blocks.
    const int bid = blockIdx.x;
    const int vx = bid & 7;
    const int tq = bid >> 3;                  // 0..287
    const int idxw = tq / 36;                 // 0..7
    const int rr0 = tq - idxw * 36;           // 0..35
    const int hg = idxw * 8 + vx;             // 0..63
    const int bg = hg >> 1;
    int r = rr0 + 36 * (hg & 1);              // 0..71
    int c2 = 0;
    while (r >= (c2 + 2) / 2) { r -= (c2 + 2) / 2; ++c2; }
    const int c1a = 2 * r;
    int c1b = 2 * r + 1;
    const bool bval = (c1b <= c2);
    if (!bval) c1b = c2;
    const int b = bg >> 4, g = bg & 15;

    const float* __restrict__ xa  = x + ((size_t)(b * NC + g * CG + c1a)) * (HH * WW);
    const float* __restrict__ xb  = x + ((size_t)(b * NC + g * CG + c1b)) * (HH * WW);
    const float* __restrict__ x2g = x + ((size_t)(b * NC + g * CG + c2 )) * (HH * WW);

    // zero pad slots [0..3] of rows 0..36 once; staging never writes pads.
    if (v < 148) smem[(v >> 2) * 196 + (v & 3)] = 0.f;

    float mid[2][25];
#pragma unroll
    for (int o = 0; o < 25; ++o) { mid[0][o] = 0.f; mid[1][o] = 0.f; }

    float win[5][5];
    float ca[5], cb[5];
#pragma unroll
    for (int k = 0; k < 5; ++k) {             // ring: ca[(u-2)%5] holds row u
        ca[k] = xa[(size_t)(2 + k) * WW + v];
        cb[k] = xb[(size_t)(2 + k) * WW + v];
    }

// One u-step. P = phase (compile-time), lbase = in-band step base (runtime,
// multiple of 5), ubase = u0 + lbase. u = ubase + P; staged row lbase+P+4 is
// the new window row (slot (P+4)%5); refill ca[P] with row u+5.
#define USTEP(P, PF)                                                          \
    {                                                                         \
        _Pragma("unroll")                                                     \
        for (int dj = 0; dj < 5; ++dj)                                        \
            win[((P) + 4) % 5][dj] = smem[(lbase + (P) + 4) * 196 + 2 + v + dj]; \
        const float a1 = ca[(P)];                                             \
        const float b1 = cb[(P)];                                             \
        if (PF) {                                                             \
            ca[(P)] = xa[(size_t)(ubase + (P) + 5) * WW + v];                 \
            cb[(P)] = xb[(size_t)(ubase + (P) + 5) * WW + v];                 \
        }                                                                     \
        _Pragma("unroll")                                                     \
        for (int kk = 0; kk < 5; ++kk) {                                      \
            _Pragma("unroll")                                                 \
            for (int dj = 0; dj < 5; ++dj) {                                  \
                const float xv = win[((P) + kk) % 5][dj];                     \
                mid[0][kk * 5 + dj] = fmaf(a1, xv, mid[0][kk * 5 + dj]);      \
                mid[1][kk * 5 + dj] = fmaf(b1, xv, mid[1][kk * 5 + dj]);      \
            }                                                                 \
        }                                                                     \
    }

    // 7 bands: 6 x 30 steps (u=2..181, 34 staged rows) + tail 8 steps
    // (u=182..189, 12 staged rows). u continuous; ring phase (u-2)%5.
    for (int band = 0; band < 7; ++band) {
        const bool full = (band < 6);
        const int u0 = 2 + band * 30;
        const int row0 = u0 - 2;
        const int nrows = full ? 34 : 12;
        const int niters = full ? 9 : 3;
        __syncthreads();
        for (int it = 0; it < niters; ++it) {
            const int rr2 = it * 4 + vr;
            if (rr2 < nrows) {
                const float4 val = *(const float4*)(x2g + (size_t)(row0 + rr2) * WW + vc4);
                *(float4*)(&smem[rr2 * 196 + 4 + vc4]) = val;
            }
        }
        __syncthreads();
        // prologue: staged rows 0..3 -> win slots 0..3
#pragma unroll
        for (int k = 0; k < 4; ++k)
#pragma unroll
        for (int dj = 0; dj < 5; ++dj)
            win[k][dj] = smem[k * 196 + 2 + v + dj];

        if (full) {
            for (int it = 0; it < 6; ++it) {          // ROLLED: body ~2.5KB
                const int lbase = it * 5;
                const int ubase = u0 + lbase;
                USTEP(0, 1) USTEP(1, 1) USTEP(2, 1) USTEP(3, 1) USTEP(4, 1)
            }
        } else {
            {   // steps 0..4 (u=182..186), refill targets 187..191 in-bounds
                const int lbase = 0;
                const int ubase = u0;
                USTEP(0, 1) USTEP(1, 1) USTEP(2, 1) USTEP(3, 1) USTEP(4, 1)
            }
            {   // steps 5..7 (u=187..189), no refill
                const int lbase = 5;
                const int ubase = u0 + 5;
                USTEP(0, 0) USTEP(1, 0) USTEP(2, 0)
            }
        }
    }
#undef USTEP

    // stage edge buffer: buf i<6 -> abs row i-2 (OOB zero), i>=6 -> 188+(i-6).
    // Row 12 = zero guard (pads catch edge-row-11 right spill); red_s at 2548.
    __syncthreads();
    for (int i = 0; i < 12; ++i) {
        const int ar = (i < 6) ? (i - 2) : (188 + i - 6);
        const float val = (ar >= 0 && ar <= 191) ? x2g[(size_t)ar * WW + v] : 0.f;
        smem[i * 196 + 4 + v] = val;
    }
    __syncthreads();

    double* const gp = gram + (size_t)bg * (PP * PP);

#pragma unroll
    for (int i1 = 0; i1 < 3; ++i1) {
        const int ra = (i1 == 0) ? 0 : ((i1 == 1) ? 1 : 190);
        const int rb = (i1 == 0) ? 1 : ((i1 == 1) ? 190 : 191);
#pragma unroll
        for (int c = 0; c < 2; ++c) {
            const float* __restrict__ xc = (c == 0) ? xa : xb;
            const float xra = xc[(size_t)ra * WW + v];
            const float xrb = xc[(size_t)rb * WW + v];
#pragma unroll
            for (int k = 0; k < 5; ++k) {
                const int bufa = (ra < 2) ? (ra + k) : (ra + k - 184);
                const int bufb = (rb < 2) ? (rb + k) : (rb + k - 184);
#pragma unroll
                for (int dj = 0; dj < 5; ++dj) {
                    float cw = mid[c][k * 5 + dj];
                    cw = fmaf(xra, smem[bufa * 196 + 2 + v + dj], cw);
                    cw = fmaf(xrb, smem[bufb * 196 + 2 + v + dj], cw);
                    red_s[v * 25 + k * 5 + dj] = cw;
                }
            }
            __syncthreads();
            float e0 = 0.f, e1 = 0.f, e190 = 0.f, e191 = 0.f;
            if (v < 25) {
                e0   = red_s[0 * 25 + v];
                e1   = red_s[1 * 25 + v];
                e190 = red_s[190 * 25 + v];
                e191 = red_s[191 * 25 + v];
            }
            __syncthreads();
            // tree reduce over columns: 192 -> 96 -> ... -> 3 (stride 25: conflict-free)
#pragma unroll
            for (int s = 96; s >= 3; s >>= 1) {
                for (int idx = v; idx < s * 25; idx += 192) {
                    const int vv = idx / 25, o = idx - vv * 25;
                    red_s[vv * 25 + o] += red_s[(vv + s) * 25 + o];
                }
                __syncthreads();
            }
            if (v < 25 && (c == 0 || bval)) {
                const int di = v / 5 - 2, dj = v - (v / 5) * 5 - 2;
                const int i2 = i1 + di;
                if (i2 >= 0 && i2 <= 2) {
                    const float S = red_s[0 * 25 + v] + red_s[1 * 25 + v] + red_s[2 * 25 + v];
                    const int c1 = (c == 0) ? c1a : c1b;
#pragma unroll
                    for (int j1 = 0; j1 < 3; ++j1) {
                        const int j2 = j1 + dj;
                        if (j2 < 0 || j2 > 2) continue;
                        const float W = S - ((j1 == 0) ? (e190 + e191)
                                          : (j1 == 1) ? (e0 + e191)
                                                      : (e0 + e1));
                        const int p = c1 * 9 + i1 * 3 + j1;
                        const int q = c2 * 9 + i2 * 3 + j2;
                        gp[p * PP + q] = (double)W;
                        if (c1 != c2) gp[q * PP + p] = (double)W;
                    }
                }
            }
            __syncthreads();   // red reused by next (i1,c)
        }
    }
}

// ---------------------------------------------------------------------------
// Kernel 2: per-group argmin (f64 d2, first-min tiebreak), bincount over both
// batches, stable top-3 (smallest index on count ties, matching lax.top_k).
// ---------------------------------------------------------------------------
__global__ __launch_bounds__(320) void topk_kernel(const double* __restrict__ gram,
                                                   float* __restrict__ pf,
                                                   int* __restrict__ pi)
{
    const int g = blockIdx.x;
    __shared__ double sdiag[2][PP];
    __shared__ int counts[PP];
    const int tid = threadIdx.x;
    if (tid < PP) counts[tid] = 0;
    if (tid < 2 * PP) {
        const int b = tid / PP, p = tid % PP;
        const double* gb = gram + (size_t)(b * 16 + g) * (PP * PP);
        sdiag[b][p] = gb[p * PP + p];
    }
    __syncthreads();
    if (tid < 2 * PP) {
        const int b = tid / PP, p = tid % PP;
        const double* row = gram + ((size_t)(b * 16 + g) * PP + p) * PP;
        const double sp = sdiag[b][p];
        double best = 1e300;
        int bi = 0;
        for (int q = 0; q < PP; ++q) {
            if (q == p) continue;
            const double d2 = sp + sdiag[b][q] - 2.0 * row[q];
            if (d2 < best) { best = d2; bi = q; }   // strict < : first occurrence
        }
        atomicAdd(&counts[bi], 1);
    }
    __syncthreads();
    if (tid == 0) {
        int sel[3], cv[3];
        for (int o = 0; o < 3; ++o) {
            int bc = -1, bp = 0;
            for (int p = 0; p < PP; ++p) {
                bool taken = false;
                for (int u = 0; u < o; ++u) if (sel[u] == p) taken = true;
                if (!taken && counts[p] > bc) { bc = counts[p]; bp = p; } // > keeps lowest idx
            }
            sel[o] = bp; cv[o] = bc;
        }
        const int tot = cv[0] + cv[1] + cv[2];
        for (int o = 0; o < 3; ++o) {
            pf[g * 4 + o] = (float)cv[o];
            pi[g * 4 + o] = sel[o];
        }
        pf[g * 4 + 3] = (float)tot;
    }
}

// ---------------------------------------------------------------------------
// Kernel 3: fused scale->floor->fold stencil. t1,t2 are plain f32 muls
// (== __fmul_rn == reference). Division via f64 reciprocal-multiply:
// bit-exact (total<=288 => exact quotients >=2^-34 rel from any f32 rounding
// midpoint, exact ties impossible, f64 error <=2^-52 -> identical rounding).
// Interior and edge in separate kernels (no divergent waves).
// ---------------------------------------------------------------------------
template <bool EDGE>
__device__ __forceinline__ void motif_quad(const float* __restrict__ x,
                                           const float* __restrict__ pf,
                                           const int* __restrict__ pi,
                                           float* __restrict__ out,
                                           int b, int ch, int h, int w0)
{
    const int g = ch >> 4;
    const size_t base = ((size_t)(b * NC + ch)) * (HH * WW);
    const float4 xv4 = *(const float4*)(x + base + (size_t)h * WW + w0);
    const float xs[4] = {xv4.x, xv4.y, xv4.z, xv4.w};
    float acc[4] = {0.f, 0.f, 0.f, 0.f};
    const float total = pf[g * 4 + 3];
    const double invd = 1.0 / (double)total;

#pragma unroll
    for (int o = 0; o < 3; ++o) {
        const int p = pi[g * 4 + o];
        const float cff = pf[g * 4 + o];
        const int co = p / 9;
        const int kk = p - co * 9;
        const int io = kk / 3, jo = kk - (kk / 3) * 3;
        const float* Rb = x + ((size_t)(b * NC + g * CG + co)) * (HH * WW);
#pragma unroll
        for (int i = 0; i < 3; ++i) {
            const int ho = h - i;
            bool rowok = true;
            int hr = ho + io;
            if (EDGE) {
                rowok = (ho >= 0) && (ho < HO);
                hr = hr < 0 ? 0 : (hr > HH - 1 ? HH - 1 : hr);
            }
            const float* row = Rb + (size_t)hr * WW;
            float rv[6];
#pragma unroll
            for (int u = 0; u < 6; ++u) {
                int col = w0 - 2 + jo + u;
                if (EDGE) col = col < 0 ? 0 : (col > WW - 1 ? WW - 1 : col);
                rv[u] = row[col];
            }
#pragma unroll
            for (int j = 0; j < 3; ++j)
#pragma unroll
            for (int q = 0; q < 4; ++q) {
                const float r2 = rv[q - j + 2];
                const float t1 = xs[q] * r2;                  // == __fmul_rn
                const float t2 = t1 * cff;                    // == __fmul_rn
                const float qf = (float)((double)t2 * invd);  // == __fdiv_rn(t2,total)
                const float vfl = floorf(qf);
                if (EDGE) {
                    const int wo = w0 + q - j;
                    const bool ok = rowok && (wo >= 0) && (wo < HO);
                    acc[q] += ok ? vfl : 0.f;
                } else {
                    acc[q] += vfl;
                }
            }
        }
    }
    float4 ov = make_float4(acc[0], acc[1], acc[2], acc[3]);
    *(float4*)(out + base + (size_t)h * WW + w0) = ov;
}

// interior: h in [2,189], w4 in [1,46] -> no clamps/masks anywhere.
__global__ __launch_bounds__(256) void out_interior(const float* __restrict__ x,
                                                    const float* __restrict__ pf,
                                                    const int* __restrict__ pi,
                                                    float* __restrict__ out)
{
    const int gid = blockIdx.x * 256 + threadIdx.x;
    const int w4i = gid % 46;
    int t = gid / 46;
    const int h = 2 + t % 188; t /= 188;
    const int ch = t & 255;
    const int b = t >> 8;
    motif_quad<false>(x, pf, pi, out, b, ch, h, (w4i + 1) * 4);
}

// edge: 568 quads per (b,ch): h in {0,1,190,191} x all 48 w4, plus
// h in [2,189] x w4 in {0,47}.
__global__ __launch_bounds__(256) void out_edge(const float* __restrict__ x,
                                                const float* __restrict__ pf,
                                                const int* __restrict__ pi,
                                                float* __restrict__ out)
{
    const int gid = blockIdx.x * 256 + threadIdx.x;
    const int e = gid % 568;
    int t = gid / 568;
    const int ch = t & 255;
    const int b = t >> 8;
    int h, w4;
    if (e < 192) {
        const int hs = e / 48;
        h = (hs < 2) ? hs : 188 + hs;         // 0,1,190,191
        w4 = e % 48;
    } else {
        const int e2 = e - 192;
        h = 2 + (e2 >> 1);
        w4 = (e2 & 1) ? 47 : 0;
    }
    motif_quad<true>(x, pf, pi, out, b, ch, h, w4 * 4);
}

// ---------------------------------------------------------------------------
extern "C" void kernel_launch(void* const* d_in, const int* in_sizes, int n_in,
                              void* d_out, int out_size, void* d_ws, size_t ws_size,
                              hipStream_t stream)
{
    const float* x = (const float*)d_in[0];
    float* out = (float*)d_out;

    double* gram = (double*)d_ws;
    const size_t gram_bytes = (size_t)32 * PP * PP * sizeof(double); // 5,308,416 B
    float* pf = (float*)((char*)d_ws + gram_bytes);
    int* pi = (int*)((char*)d_ws + gram_bytes + 256);

    gram_kernel<<<2304, 192, 0, stream>>>(x, gram);
    topk_kernel<<<16, 320, 0, stream>>>(gram, pf, pi);
    out_interior<<<17296, 256, 0, stream>>>(x, pf, pi, out);  // 2*256*188*46/256
    out_edge<<<1136, 256, 0, stream>>>(x, pf, pi, out);       // 2*256*568/256
}